// Round 6
// baseline (534.076 us; speedup 1.0000x reference)
//
#include <hip/hip_runtime.h>
#include <hip/hip_bf16.h>

// ---------------------------------------------------------------------------
// SingleHeadAttention: b=8, t=2048, e=1024. I/O = float32.
//   Q = (q @ Wq^T)/e^0.25 ; K = (k @ Wk^T)/e^0.25 ; V = v @ Wv^T
//   S = Q K^T (causal) ; P = softmax(S) ; O = P V
// bf16 MFMA internals, f32 accumulate, f32 output.
//
// Round-11: score/out rewritten as 256^2-tile / 512-thread / 8-wave kernels.
// Five rounds of 128^2 restructuring left proj AND score/out pinned at
// MfmaUtil ~21% (the 2-barrier stage+drain chain is ~72% of the critical
// path, m233). The catalog's measured fix at K=1024 is the 256^2 2-phase
// tile (m230/m248: 655-682 TF refcheck'd vs our ~290): 64 MFMA/wave/step
// doubles the MFMA:stall ratio. Same proven primitives (chunked gload_lds,
// XOR swizzle, 1-phase barrier pair), wave grid 2x4, acc[8][4].
//  - proj: reverted verbatim to round-1 (its measured best, 195us).
//  - softmax: pad granularity 128 -> 256 (out now reads P up to the
//    256-aligned causal boundary; the masked strip must be exp->0, not
//    raw -1e30).  <- correctness-critical with 256-wide out tiles.
//  - out: br reversed (longest causal blocks first), ksteps=(br+1)*4.
//  - ws: [Q][K][Vt][S]; bf16 weights alias the dead S region during proj.
// ---------------------------------------------------------------------------

typedef short short8 __attribute__((ext_vector_type(8)));   // 8 x bf16
typedef float f32x4 __attribute__((ext_vector_type(4)));
typedef int   int4v __attribute__((ext_vector_type(4)));

static constexpr int B_ = 8;
static constexpr int T_ = 2048;
static constexpr int E_ = 1024;

__device__ __forceinline__ float bf2f(ushort u) {
    union { unsigned int i; float f; } x; x.i = ((unsigned int)u) << 16; return x.f;
}
__device__ __forceinline__ ushort f2bf(float f) {
    union { float f; unsigned int i; } x; x.f = f;
    unsigned int r = x.i + 0x7fffu + ((x.i >> 16) & 1u);   // RNE
    return (ushort)(r >> 16);
}
// packed f32x8 -> bf16x8 (RNE)
__device__ __forceinline__ short8 cvt8(f32x4 a, f32x4 b) {
    short8 r;
    union { __hip_bfloat162 h; unsigned int u; } p;
    unsigned int* ru = (unsigned int*)&r;
    p.h = __float22bfloat162_rn(make_float2(a[0], a[1])); ru[0] = p.u;
    p.h = __float22bfloat162_rn(make_float2(a[2], a[3])); ru[1] = p.u;
    p.h = __float22bfloat162_rn(make_float2(b[0], b[1])); ru[2] = p.u;
    p.h = __float22bfloat162_rn(make_float2(b[2], b[3])); ru[3] = p.u;
    return r;
}

// async 16B global -> LDS; lds base wave-uniform, lane i lands at +16*i.
__device__ __forceinline__ void async16(const ushort* g, ushort* l) {
    __builtin_amdgcn_global_load_lds(
        (const __attribute__((address_space(1))) unsigned int*)g,
        (__attribute__((address_space(3))) unsigned int*)l, 16, 0, 0);
}
__device__ __forceinline__ void async16f(const float* g, float* l) {
    __builtin_amdgcn_global_load_lds(
        (const __attribute__((address_space(1))) unsigned int*)g,
        (__attribute__((address_space(3))) unsigned int*)l, 16, 0, 0);
}

// ---------------------------------------------------------------------------
// 256x256 NT GEMM tile, 512 threads (8 waves, 2x4), BK=64, 1-phase.
// LDS 256x64 bf16 per operand (32 KB each). Row = 8 granules of 16B;
// LDS (r,g) holds global (r, g ^ (r&7)) -> conflict-free b128 frag reads.
// Per wave per K-step: 64 MFMA (2x the 128^2 tile's MFMA:stall ratio).
__device__ __forceinline__ void gemm_tile256(const ushort* __restrict__ A, int lda,
                                             const ushort* __restrict__ Bm, int ldb,
                                             int ksteps, f32x4 (&acc)[8][4],
                                             ushort* As, ushort* Bs)
{
    const int tid = threadIdx.x, lane = tid & 63, wave = tid >> 6;   // 0..7
    const int wr = (wave >> 2) * 128;          // A row base (2 wave-rows)
    const int wc = (wave & 3) * 64;            // B row base (4 wave-cols)
    const int srow = lane >> 3;                // row within 8-row chunk
    const int scol = ((lane & 7) ^ srow) * 8;  // swizzled source col (elems)
    const int frow = lane & 15, q4 = lane >> 4;

    for (int ks = 0; ks < ksteps; ++ks) {
        const int k0 = ks * 64;
        __syncthreads();   // prior iter's ds_reads complete before overwrite
#pragma unroll
        for (int j = 0; j < 4; ++j) {
            const int c = wave * 4 + j;        // 32 chunks of 8 rows per operand
            const int grow = c * 8 + srow;
            async16(A  + (size_t)grow * lda + k0 + scol, As + c * 512);
            async16(Bm + (size_t)grow * ldb + k0 + scol, Bs + c * 512);
        }
        __syncthreads();   // drains vmcnt(0)

#pragma unroll
        for (int kk = 0; kk < 2; ++kk) {
            short8 af[8], bf[4];
            const int sw = frow & 7;
            const int g = (kk * 4 + q4) ^ sw;
#pragma unroll
            for (int i = 0; i < 8; ++i) {
                const int ra = wr + i * 16 + frow;
                af[i] = *(const short8*)(As + ra * 64 + g * 8);
            }
#pragma unroll
            for (int n = 0; n < 4; ++n) {
                const int rb = wc + n * 16 + frow;
                bf[n] = *(const short8*)(Bs + rb * 64 + g * 8);
            }
#pragma unroll
            for (int mi = 0; mi < 8; ++mi)
#pragma unroll
                for (int ni = 0; ni < 4; ++ni)
                    acc[mi][ni] = __builtin_amdgcn_mfma_f32_16x16x32_bf16(
                        af[mi], bf[ni], acc[mi][ni], 0, 0, 0);
        }
    }
}

// ---------------------------------------------------------------------------
// Weight converter: three 1024x1024 f32 -> bf16 (grid.y = 3).
__global__ __launch_bounds__(256)
void cvtW_kernel(const float* __restrict__ w0, const float* __restrict__ w1,
                 const float* __restrict__ w2, ushort* __restrict__ d)
{
    const float* s = blockIdx.y == 0 ? w0 : (blockIdx.y == 1 ? w1 : w2);
    ushort* dd = d + (size_t)blockIdx.y * E_ * E_;
    const int idx = (blockIdx.x * 256 + threadIdx.x) * 8;
    f32x4 a = *(const f32x4*)(s + idx);
    f32x4 b = *(const f32x4*)(s + idx + 4);
    *(short8*)(dd + idx) = cvt8(a, b);
}

// ---------------------------------------------------------------------------
// Stage 1: all three projections, one dispatch. grid (128, 8, 3). BK=64.
// (Round-1 version verbatim -- its measured best, 195us.)
// A tile: 128x64 f32 (32 KB), 16 granules/row of 16B, swz g^(r&7).
// B tile: 128x64 bf16 (16 KB), 8 granules/row, swz g^(r&7).
__global__ __launch_bounds__(256, 2)
void proj_kernel(const float* __restrict__ q, const float* __restrict__ k,
                 const float* __restrict__ v, const ushort* __restrict__ Wb,
                 ushort* __restrict__ Q, ushort* __restrict__ Kp,
                 ushort* __restrict__ Vt)
{
    __shared__ float  Asf[128 * 64];    // 32 KB
    __shared__ ushort Bs[128 * 64];     // 16 KB
    const int z = blockIdx.z;
    const float* A = (z == 0 ? q : (z == 1 ? k : v)) + (size_t)blockIdx.x * 128 * E_;
    const ushort* W = Wb + (size_t)z * E_ * E_ + (size_t)blockIdx.y * 128 * E_;

    const int tid = threadIdx.x, lane = tid & 63, wave = tid >> 6;
    const int wr = (wave >> 1) * 64, wc = (wave & 1) * 64;
    const int aRowIn = lane >> 4;
    const int bRowIn = lane >> 3;
    const int frow = lane & 15, q4 = lane >> 4;

    f32x4 acc[4][4];
#pragma unroll
    for (int i = 0; i < 4; ++i)
#pragma unroll
        for (int j = 0; j < 4; ++j) acc[i][j] = (f32x4){0.f, 0.f, 0.f, 0.f};

    for (int ks = 0; ks < E_ / 64; ++ks) {
        const int k0 = ks * 64;
        __syncthreads();
        // A: 8 chunks per wave (32 chunks of 4 rows)
#pragma unroll
        for (int j = 0; j < 8; ++j) {
            const int c = wave * 8 + j;
            const int row = c * 4 + aRowIn;
            const int sg = (lane & 15) ^ (row & 7);
            async16f(A + (size_t)row * E_ + k0 + sg * 4, Asf + c * 256);
        }
        // B: 4 chunks per wave (16 chunks of 8 rows)
#pragma unroll
        for (int j = 0; j < 4; ++j) {
            const int c = wave * 4 + j;
            const int row = c * 8 + bRowIn;
            const int sg = (lane & 7) ^ (row & 7);
            async16(W + (size_t)row * E_ + k0 + sg * 8, Bs + c * 512);
        }
        __syncthreads();   // drains vmcnt(0)

#pragma unroll
        for (int kk = 0; kk < 2; ++kk) {
            short8 af[4], bf[4];
#pragma unroll
            for (int i = 0; i < 4; ++i) {
                const int Ra = wr + i * 16 + frow;
                const int sw = frow & 7;
                const int g0 = (kk * 8 + q4 * 2) ^ sw;
                const int g1 = g0 ^ 1;
                f32x4 lo = *(const f32x4*)(Asf + Ra * 64 + g0 * 4);
                f32x4 hi = *(const f32x4*)(Asf + Ra * 64 + g1 * 4);
                af[i] = cvt8(lo, hi);
                const int Rb = wc + i * 16 + frow;
                const int gb = (kk * 4 + q4) ^ sw;
                bf[i] = *(const short8*)(Bs + Rb * 64 + gb * 8);
            }
#pragma unroll
            for (int mi = 0; mi < 4; ++mi)
#pragma unroll
                for (int ni = 0; ni < 4; ++ni)
                    acc[mi][ni] = __builtin_amdgcn_mfma_f32_16x16x32_bf16(
                        af[mi], bf[ni], acc[mi][ni], 0, 0, 0);
        }
    }

    const float scale = (z == 2) ? 1.0f : 0.17677669529663687f;  // 1/e^(1/4)
    if (z < 2) {
        ushort* D = (z == 0 ? Q : Kp);
#pragma unroll
        for (int mi = 0; mi < 4; ++mi)
#pragma unroll
            for (int r = 0; r < 4; ++r) {
                const int row = blockIdx.x * 128 + wr + mi * 16 + (lane >> 4) * 4 + r;
#pragma unroll
                for (int ni = 0; ni < 4; ++ni) {
                    const int col = blockIdx.y * 128 + wc + ni * 16 + (lane & 15);
                    D[(size_t)row * E_ + col] = f2bf(acc[mi][ni][r] * scale);
                }
            }
    } else {
#pragma unroll
        for (int mi = 0; mi < 4; ++mi)
#pragma unroll
            for (int r = 0; r < 4; ++r) {
                const int rowg = blockIdx.x * 128 + wr + mi * 16 + (lane >> 4) * 4 + r;
                const int bb = rowg >> 11, tl = rowg & 2047;
#pragma unroll
                for (int ni = 0; ni < 4; ++ni) {
                    const int col = blockIdx.y * 128 + wc + ni * 16 + (lane & 15);
                    Vt[(size_t)bb * E_ * T_ + (size_t)col * T_ + tl] = f2bf(acc[mi][ni][r]);
                }
            }
    }
}

// ---------------------------------------------------------------------------
// Stage 2: S = Q K^T causal. 256^2 tiles, compact lower-triangle grid (36, 8).
__global__ __launch_bounds__(512, 2)
void score_kernel(const ushort* __restrict__ Q, const ushort* __restrict__ K,
                  ushort* __restrict__ S)
{
    __shared__ ushort As[256 * 64];   // 32 KB
    __shared__ ushort Bs[256 * 64];   // 32 KB
    const int t = blockIdx.x, b = blockIdx.y;
    int br = (int)((sqrtf(8.0f * t + 1.0f) - 1.0f) * 0.5f);
    while ((br + 1) * (br + 2) / 2 <= t) ++br;
    while (br * (br + 1) / 2 > t) --br;
    const int bc = t - br * (br + 1) / 2;

    const ushort* A  = Q + ((size_t)b * T_ + br * 256) * E_;
    const ushort* Bm = K + ((size_t)b * T_ + bc * 256) * E_;

    f32x4 acc[8][4];
#pragma unroll
    for (int i = 0; i < 8; ++i)
#pragma unroll
        for (int j = 0; j < 4; ++j) acc[i][j] = (f32x4){0.f, 0.f, 0.f, 0.f};

    gemm_tile256(A, E_, Bm, E_, E_ / 64, acc, As, Bs);

    const int lane = threadIdx.x & 63, wave = threadIdx.x >> 6;
    const int wr = (wave >> 2) * 128, wc = (wave & 3) * 64;
    const int frow = lane & 15, q4 = lane >> 4;
    ushort* Sb = S + (size_t)b * T_ * T_;
#pragma unroll
    for (int mi = 0; mi < 8; ++mi)
#pragma unroll
        for (int r = 0; r < 4; ++r) {
            const int row = br * 256 + wr + mi * 16 + q4 * 4 + r;
#pragma unroll
            for (int ni = 0; ni < 4; ++ni) {
                const int col = bc * 256 + wc + ni * 16 + frow;
                float val = acc[mi][ni][r];
                if (col > row) val = -1e30f;
                Sb[(size_t)row * T_ + col] = f2bf(val);
            }
        }
}

// ---------------------------------------------------------------------------
// Stage 3: row softmax in place, 16B vector I/O. One block per row.
// Pad granularity 256 (out reads P up to the 256-aligned causal boundary;
// the masked -1e30 strip must be normalized to exp->0).
__global__ __launch_bounds__(256)
void softmax_kernel(ushort* __restrict__ S)
{
    const int gr = blockIdx.x;
    const int b = gr >> 11, i = gr & 2047;
    ushort* row = S + (size_t)b * T_ * T_ + (size_t)i * T_;
    const int Lpad = ((i >> 8) + 1) * 256;
    const int tid = threadIdx.x, lane = tid & 63, wave = tid >> 6;
    __shared__ float red[4];

    const int j0 = tid * 8;
    const bool act = j0 < Lpad;
    float xv[8];
    if (act) {
        int4v dv = *(const int4v*)(row + j0);
        const ushort* u = (const ushort*)&dv;
#pragma unroll
        for (int t = 0; t < 8; ++t) xv[t] = bf2f(u[t]);
    }

    float m = -1e30f;
    if (act)
#pragma unroll
        for (int t = 0; t < 8; ++t) m = fmaxf(m, xv[t]);
#pragma unroll
    for (int o = 32; o; o >>= 1) m = fmaxf(m, __shfl_xor(m, o, 64));
    if (lane == 0) red[wave] = m;
    __syncthreads();
    m = fmaxf(fmaxf(red[0], red[1]), fmaxf(red[2], red[3]));
    __syncthreads();

    float s = 0.f;
    if (act)
#pragma unroll
        for (int t = 0; t < 8; ++t) { xv[t] = __expf(xv[t] - m); s += xv[t]; }
#pragma unroll
    for (int o = 32; o; o >>= 1) s += __shfl_xor(s, o, 64);
    if (lane == 0) red[wave] = s;
    __syncthreads();
    s = red[0] + red[1] + red[2] + red[3];
    const float inv = 1.0f / s;

    if (act) {
        int4v dv;
        ushort* u = (ushort*)&dv;
#pragma unroll
        for (int t = 0; t < 8; ++t) u[t] = f2bf(xv[t] * inv);
        *(int4v*)(row + j0) = dv;
    }
}

// ---------------------------------------------------------------------------
// Stage 4: O = P @ V via V^T (NT, BK=64). 256^2 tiles, grid (4, 8, 8).
// br reversed so the longest causal blocks (br=7, 32 ksteps) dispatch first.
__global__ __launch_bounds__(512, 2)
void out_kernel(const ushort* __restrict__ P, const ushort* __restrict__ Vt,
                float* __restrict__ O)
{
    __shared__ ushort As[256 * 64];   // 32 KB
    __shared__ ushort Bs[256 * 64];   // 32 KB
    const int bc = blockIdx.x, b = blockIdx.z;
    const int br = (int)gridDim.y - 1 - (int)blockIdx.y;   // longest first
    const ushort* A  = P  + (size_t)b * T_ * T_ + (size_t)(br * 256) * T_;
    const ushort* Bm = Vt + (size_t)b * E_ * T_ + (size_t)(bc * 256) * T_;
    const int ksteps = (br + 1) * 4;   // causal K-limit, BK=64

    f32x4 acc[8][4];
#pragma unroll
    for (int i = 0; i < 8; ++i)
#pragma unroll
        for (int j = 0; j < 4; ++j) acc[i][j] = (f32x4){0.f, 0.f, 0.f, 0.f};

    gemm_tile256(A, T_, Bm, T_, ksteps, acc, As, Bs);

    const int lane = threadIdx.x & 63, wave = threadIdx.x >> 6;
    const int wr = (wave >> 2) * 128, wc = (wave & 3) * 64;
    const int frow = lane & 15, q4 = lane >> 4;
    float* Ob = O + (size_t)b * T_ * E_;
#pragma unroll
    for (int mi = 0; mi < 8; ++mi)
#pragma unroll
        for (int r = 0; r < 4; ++r) {
            const int row = br * 256 + wr + mi * 16 + q4 * 4 + r;
#pragma unroll
            for (int ni = 0; ni < 4; ++ni) {
                const int col = bc * 256 + wc + ni * 16 + frow;
                Ob[(size_t)row * E_ + col] = acc[mi][ni][r];
            }
        }
}

// ---------------------------------------------------------------------------
extern "C" void kernel_launch(void* const* d_in, const int* in_sizes, int n_in,
                              void* d_out, int out_size, void* d_ws, size_t ws_size,
                              hipStream_t stream)
{
    const float* q  = (const float*)d_in[0];
    const float* k  = (const float*)d_in[1];
    const float* v  = (const float*)d_in[2];
    const float* Wq = (const float*)d_in[3];
    const float* Wk = (const float*)d_in[4];
    const float* Wv = (const float*)d_in[5];
    float* out = (float*)d_out;

    const size_t nQKV = (size_t)B_ * T_ * E_;      // 16,777,216 elems
    const size_t nW   = (size_t)E_ * E_;
    ushort* Q  = (ushort*)d_ws;
    ushort* K  = Q + nQKV;
    ushort* Vt = K + nQKV;
    ushort* S  = Vt + nQKV;                        // 67 MB
    ushort* Wb = S;                                // weights alias dead S region

    cvtW_kernel<<<dim3(nW / 2048, 3), 256, 0, stream>>>(Wq, Wk, Wv, Wb);
    proj_kernel<<<dim3(128, 8, 3), 256, 0, stream>>>(q, k, v, Wb, Q, K, Vt);
    score_kernel<<<dim3(36, B_), 512, 0, stream>>>(Q, K, S);
    softmax_kernel<<<dim3(B_ * T_), 256, 0, stream>>>(S);
    out_kernel<<<dim3(4, 8, B_), 512, 0, stream>>>(S, Vt, out);
}

// Round 7
// 497.796 us; speedup vs baseline: 1.0729x; 1.0729x over previous
//
#include <hip/hip_runtime.h>
#include <hip/hip_bf16.h>

// ---------------------------------------------------------------------------
// SingleHeadAttention: b=8, t=2048, e=1024. I/O = float32.
//   Q = (q @ Wq^T)/e^0.25 ; K = (k @ Wk^T)/e^0.25 ; V = v @ Wv^T
//   S = Q K^T (causal) ; P = softmax(S) ; O = P V
// bf16 MFMA internals, f32 accumulate, f32 output.
//
// Round-12: score/out as 256x128-tile / 4-wave kernels (fix r11's packing).
// r11's 256^2 512-thread blocks needed ~210 VGPR -> 1 block/CU, grids of
// 256-288 blocks -> no inter-block overlap + ~56% packing + out imbalance
// (1 block/CU => duration=max(ksteps) not mean). This round keeps the
// 64-MFMA/wave/step ratio (the real win of 256-class tiles) via 256x128
// tiles, 4 waves (2x2), per-wave 128x64 (acc[8][4]): 48 KB LDS, ~206 VGPR
// -> 2 blocks/CU resident.
//  - score: compact triangle (br 256-rows x bc 128-cols) = 72 x 8 blocks,
//    uniform 16 ksteps.
//  - out: grid (8,8,8); br = base[y]^(z<4?0:7), base={7,6,5,4,0,1,2,3} so
//    the two blocks per CU sum to a constant 36 ksteps (complement pairing).
//  - proj: round-1 form verbatim (197us, reproduced 3x).
//  - softmax: 256-granular pad (out reads P to the 256-aligned boundary).
//  - ws: [Q][K][Vt][S]; bf16 weights alias the dead S region during proj.
// ---------------------------------------------------------------------------

typedef short short8 __attribute__((ext_vector_type(8)));   // 8 x bf16
typedef float f32x4 __attribute__((ext_vector_type(4)));
typedef int   int4v __attribute__((ext_vector_type(4)));

static constexpr int B_ = 8;
static constexpr int T_ = 2048;
static constexpr int E_ = 1024;

__device__ __forceinline__ float bf2f(ushort u) {
    union { unsigned int i; float f; } x; x.i = ((unsigned int)u) << 16; return x.f;
}
__device__ __forceinline__ ushort f2bf(float f) {
    union { float f; unsigned int i; } x; x.f = f;
    unsigned int r = x.i + 0x7fffu + ((x.i >> 16) & 1u);   // RNE
    return (ushort)(r >> 16);
}
// packed f32x8 -> bf16x8 (RNE)
__device__ __forceinline__ short8 cvt8(f32x4 a, f32x4 b) {
    short8 r;
    union { __hip_bfloat162 h; unsigned int u; } p;
    unsigned int* ru = (unsigned int*)&r;
    p.h = __float22bfloat162_rn(make_float2(a[0], a[1])); ru[0] = p.u;
    p.h = __float22bfloat162_rn(make_float2(a[2], a[3])); ru[1] = p.u;
    p.h = __float22bfloat162_rn(make_float2(b[0], b[1])); ru[2] = p.u;
    p.h = __float22bfloat162_rn(make_float2(b[2], b[3])); ru[3] = p.u;
    return r;
}

// async 16B global -> LDS; lds base wave-uniform, lane i lands at +16*i.
__device__ __forceinline__ void async16(const ushort* g, ushort* l) {
    __builtin_amdgcn_global_load_lds(
        (const __attribute__((address_space(1))) unsigned int*)g,
        (__attribute__((address_space(3))) unsigned int*)l, 16, 0, 0);
}
__device__ __forceinline__ void async16f(const float* g, float* l) {
    __builtin_amdgcn_global_load_lds(
        (const __attribute__((address_space(1))) unsigned int*)g,
        (__attribute__((address_space(3))) unsigned int*)l, 16, 0, 0);
}

// ---------------------------------------------------------------------------
// 256(M) x 128(N) NT GEMM tile, 256 threads (4 waves, 2x2), BK=64, 1-phase.
// Per-wave output 128x64 -> acc[8][4], 64 MFMA/wave/K-step.
// LDS: A 256x64 bf16 (32 KB), B 128x64 bf16 (16 KB). Row = 8 granules of
// 16B; LDS (r,g) holds global (r, g ^ (r&7)) -> conflict-free b128 reads.
__device__ __forceinline__ void gemm_tile256x128(const ushort* __restrict__ A, int lda,
                                                 const ushort* __restrict__ Bm, int ldb,
                                                 int ksteps, f32x4 (&acc)[8][4],
                                                 ushort* As, ushort* Bs)
{
    const int tid = threadIdx.x, lane = tid & 63, wave = tid >> 6;   // 0..3
    const int wr = (wave >> 1) * 128;          // A row base
    const int wc = (wave & 1) * 64;            // B row base
    const int srow = lane >> 3;                // row within 8-row chunk
    const int scol = ((lane & 7) ^ srow) * 8;  // swizzled source col (elems)
    const int frow = lane & 15, q4 = lane >> 4;

    for (int ks = 0; ks < ksteps; ++ks) {
        const int k0 = ks * 64;
        __syncthreads();   // prior iter's ds_reads complete before overwrite
        // A: 32 chunks of 8 rows -> 8 per wave
#pragma unroll
        for (int j = 0; j < 8; ++j) {
            const int c = wave * 8 + j;
            const int grow = c * 8 + srow;
            async16(A + (size_t)grow * lda + k0 + scol, As + c * 512);
        }
        // B: 16 chunks of 8 rows -> 4 per wave
#pragma unroll
        for (int j = 0; j < 4; ++j) {
            const int c = wave * 4 + j;
            const int grow = c * 8 + srow;
            async16(Bm + (size_t)grow * ldb + k0 + scol, Bs + c * 512);
        }
        __syncthreads();   // drains vmcnt(0)

#pragma unroll
        for (int kk = 0; kk < 2; ++kk) {
            short8 af[8], bf[4];
            const int g = (kk * 4 + q4) ^ (frow & 7);
#pragma unroll
            for (int i = 0; i < 8; ++i) {
                const int ra = wr + i * 16 + frow;
                af[i] = *(const short8*)(As + ra * 64 + g * 8);
            }
#pragma unroll
            for (int n = 0; n < 4; ++n) {
                const int rb = wc + n * 16 + frow;
                bf[n] = *(const short8*)(Bs + rb * 64 + g * 8);
            }
#pragma unroll
            for (int mi = 0; mi < 8; ++mi)
#pragma unroll
                for (int ni = 0; ni < 4; ++ni)
                    acc[mi][ni] = __builtin_amdgcn_mfma_f32_16x16x32_bf16(
                        af[mi], bf[ni], acc[mi][ni], 0, 0, 0);
        }
    }
}

// ---------------------------------------------------------------------------
// Weight converter: three 1024x1024 f32 -> bf16 (grid.y = 3).
__global__ __launch_bounds__(256)
void cvtW_kernel(const float* __restrict__ w0, const float* __restrict__ w1,
                 const float* __restrict__ w2, ushort* __restrict__ d)
{
    const float* s = blockIdx.y == 0 ? w0 : (blockIdx.y == 1 ? w1 : w2);
    ushort* dd = d + (size_t)blockIdx.y * E_ * E_;
    const int idx = (blockIdx.x * 256 + threadIdx.x) * 8;
    f32x4 a = *(const f32x4*)(s + idx);
    f32x4 b = *(const f32x4*)(s + idx + 4);
    *(short8*)(dd + idx) = cvt8(a, b);
}

// ---------------------------------------------------------------------------
// Stage 1: all three projections, one dispatch. grid (128, 8, 3). BK=64.
// (Round-1 version verbatim -- its measured best, ~197us, reproduced 3x.)
__global__ __launch_bounds__(256, 2)
void proj_kernel(const float* __restrict__ q, const float* __restrict__ k,
                 const float* __restrict__ v, const ushort* __restrict__ Wb,
                 ushort* __restrict__ Q, ushort* __restrict__ Kp,
                 ushort* __restrict__ Vt)
{
    __shared__ float  Asf[128 * 64];    // 32 KB
    __shared__ ushort Bs[128 * 64];     // 16 KB
    const int z = blockIdx.z;
    const float* A = (z == 0 ? q : (z == 1 ? k : v)) + (size_t)blockIdx.x * 128 * E_;
    const ushort* W = Wb + (size_t)z * E_ * E_ + (size_t)blockIdx.y * 128 * E_;

    const int tid = threadIdx.x, lane = tid & 63, wave = tid >> 6;
    const int wr = (wave >> 1) * 64, wc = (wave & 1) * 64;
    const int aRowIn = lane >> 4;
    const int bRowIn = lane >> 3;
    const int frow = lane & 15, q4 = lane >> 4;

    f32x4 acc[4][4];
#pragma unroll
    for (int i = 0; i < 4; ++i)
#pragma unroll
        for (int j = 0; j < 4; ++j) acc[i][j] = (f32x4){0.f, 0.f, 0.f, 0.f};

    for (int ks = 0; ks < E_ / 64; ++ks) {
        const int k0 = ks * 64;
        __syncthreads();
#pragma unroll
        for (int j = 0; j < 8; ++j) {
            const int c = wave * 8 + j;
            const int row = c * 4 + aRowIn;
            const int sg = (lane & 15) ^ (row & 7);
            async16f(A + (size_t)row * E_ + k0 + sg * 4, Asf + c * 256);
        }
#pragma unroll
        for (int j = 0; j < 4; ++j) {
            const int c = wave * 4 + j;
            const int row = c * 8 + bRowIn;
            const int sg = (lane & 7) ^ (row & 7);
            async16(W + (size_t)row * E_ + k0 + sg * 8, Bs + c * 512);
        }
        __syncthreads();   // drains vmcnt(0)

#pragma unroll
        for (int kk = 0; kk < 2; ++kk) {
            short8 af[4], bf[4];
#pragma unroll
            for (int i = 0; i < 4; ++i) {
                const int Ra = wr + i * 16 + frow;
                const int sw = frow & 7;
                const int g0 = (kk * 8 + q4 * 2) ^ sw;
                const int g1 = g0 ^ 1;
                f32x4 lo = *(const f32x4*)(Asf + Ra * 64 + g0 * 4);
                f32x4 hi = *(const f32x4*)(Asf + Ra * 64 + g1 * 4);
                af[i] = cvt8(lo, hi);
                const int Rb = wc + i * 16 + frow;
                const int gb = (kk * 4 + q4) ^ sw;
                bf[i] = *(const short8*)(Bs + Rb * 64 + gb * 8);
            }
#pragma unroll
            for (int mi = 0; mi < 4; ++mi)
#pragma unroll
                for (int ni = 0; ni < 4; ++ni)
                    acc[mi][ni] = __builtin_amdgcn_mfma_f32_16x16x32_bf16(
                        af[mi], bf[ni], acc[mi][ni], 0, 0, 0);
        }
    }

    const float scale = (z == 2) ? 1.0f : 0.17677669529663687f;  // 1/e^(1/4)
    if (z < 2) {
        ushort* D = (z == 0 ? Q : Kp);
#pragma unroll
        for (int mi = 0; mi < 4; ++mi)
#pragma unroll
            for (int r = 0; r < 4; ++r) {
                const int row = blockIdx.x * 128 + wr + mi * 16 + (lane >> 4) * 4 + r;
#pragma unroll
                for (int ni = 0; ni < 4; ++ni) {
                    const int col = blockIdx.y * 128 + wc + ni * 16 + (lane & 15);
                    D[(size_t)row * E_ + col] = f2bf(acc[mi][ni][r] * scale);
                }
            }
    } else {
#pragma unroll
        for (int mi = 0; mi < 4; ++mi)
#pragma unroll
            for (int r = 0; r < 4; ++r) {
                const int rowg = blockIdx.x * 128 + wr + mi * 16 + (lane >> 4) * 4 + r;
                const int bb = rowg >> 11, tl = rowg & 2047;
#pragma unroll
                for (int ni = 0; ni < 4; ++ni) {
                    const int col = blockIdx.y * 128 + wc + ni * 16 + (lane & 15);
                    Vt[(size_t)bb * E_ * T_ + (size_t)col * T_ + tl] = f2bf(acc[mi][ni][r]);
                }
            }
    }
}

// ---------------------------------------------------------------------------
// Stage 2: S = Q K^T causal. 256x128 tiles, compact triangle grid (72, 8).
// Row-block br (256 rows) has 2br+2 col-blocks (128 cols): t = br(br+1)+bc.
__global__ __launch_bounds__(256, 2)
void score_kernel(const ushort* __restrict__ Q, const ushort* __restrict__ K,
                  ushort* __restrict__ S)
{
    __shared__ ushort As[256 * 64];   // 32 KB
    __shared__ ushort Bs[128 * 64];   // 16 KB
    const int t = blockIdx.x, b = blockIdx.y;
    int br = (int)((sqrtf(4.0f * t + 1.0f) - 1.0f) * 0.5f);
    while ((br + 1) * (br + 2) <= t) ++br;
    while (br * (br + 1) > t) --br;
    const int bc = t - br * (br + 1);

    const ushort* A  = Q + ((size_t)b * T_ + br * 256) * E_;
    const ushort* Bm = K + ((size_t)b * T_ + bc * 128) * E_;

    f32x4 acc[8][4];
#pragma unroll
    for (int i = 0; i < 8; ++i)
#pragma unroll
        for (int j = 0; j < 4; ++j) acc[i][j] = (f32x4){0.f, 0.f, 0.f, 0.f};

    gemm_tile256x128(A, E_, Bm, E_, E_ / 64, acc, As, Bs);

    const int lane = threadIdx.x & 63, wave = threadIdx.x >> 6;
    const int wr = (wave >> 1) * 128, wc = (wave & 1) * 64;
    const int frow = lane & 15, q4 = lane >> 4;
    ushort* Sb = S + (size_t)b * T_ * T_;
#pragma unroll
    for (int mi = 0; mi < 8; ++mi)
#pragma unroll
        for (int r = 0; r < 4; ++r) {
            const int row = br * 256 + wr + mi * 16 + q4 * 4 + r;
#pragma unroll
            for (int ni = 0; ni < 4; ++ni) {
                const int col = bc * 128 + wc + ni * 16 + frow;
                float val = acc[mi][ni][r];
                if (col > row) val = -1e30f;
                Sb[(size_t)row * T_ + col] = f2bf(val);
            }
        }
}

// ---------------------------------------------------------------------------
// Stage 3: row softmax in place, 16B vector I/O. One block per row.
// Pad granularity 256 (out reads P up to the 256-aligned causal boundary;
// the masked -1e30 strip must be normalized to exp->0).
__global__ __launch_bounds__(256)
void softmax_kernel(ushort* __restrict__ S)
{
    const int gr = blockIdx.x;
    const int b = gr >> 11, i = gr & 2047;
    ushort* row = S + (size_t)b * T_ * T_ + (size_t)i * T_;
    const int Lpad = ((i >> 8) + 1) * 256;
    const int tid = threadIdx.x, lane = tid & 63, wave = tid >> 6;
    __shared__ float red[4];

    const int j0 = tid * 8;
    const bool act = j0 < Lpad;
    float xv[8];
    if (act) {
        int4v dv = *(const int4v*)(row + j0);
        const ushort* u = (const ushort*)&dv;
#pragma unroll
        for (int t = 0; t < 8; ++t) xv[t] = bf2f(u[t]);
    }

    float m = -1e30f;
    if (act)
#pragma unroll
        for (int t = 0; t < 8; ++t) m = fmaxf(m, xv[t]);
#pragma unroll
    for (int o = 32; o; o >>= 1) m = fmaxf(m, __shfl_xor(m, o, 64));
    if (lane == 0) red[wave] = m;
    __syncthreads();
    m = fmaxf(fmaxf(red[0], red[1]), fmaxf(red[2], red[3]));
    __syncthreads();

    float s = 0.f;
    if (act)
#pragma unroll
        for (int t = 0; t < 8; ++t) { xv[t] = __expf(xv[t] - m); s += xv[t]; }
#pragma unroll
    for (int o = 32; o; o >>= 1) s += __shfl_xor(s, o, 64);
    if (lane == 0) red[wave] = s;
    __syncthreads();
    s = red[0] + red[1] + red[2] + red[3];
    const float inv = 1.0f / s;

    if (act) {
        int4v dv;
        ushort* u = (ushort*)&dv;
#pragma unroll
        for (int t = 0; t < 8; ++t) u[t] = f2bf(xv[t] * inv);
        *(int4v*)(row + j0) = dv;
    }
}

// ---------------------------------------------------------------------------
// Stage 4: O = P @ V via V^T (NT, BK=64). 256x128 tiles, grid (8, 8, 8).
// br = base[y] ^ (z<4 ? 0 : 7), base = {7,6,5,4,0,1,2,3}: with round-robin
// block->CU dispatch, the two blocks resident per CU have complementary
// ksteps summing to a constant 36 -> balanced finish times.
__global__ __launch_bounds__(256, 2)
void out_kernel(const ushort* __restrict__ P, const ushort* __restrict__ Vt,
                float* __restrict__ O)
{
    __shared__ ushort As[256 * 64];   // 32 KB
    __shared__ ushort Bs[128 * 64];   // 16 KB
    const int bc = blockIdx.x, b = blockIdx.z;
    const int y = blockIdx.y;
    const int base = (y < 4) ? (7 - y) : (y - 4);
    const int br = base ^ ((blockIdx.z < 4) ? 0 : 7);
    const ushort* A  = P  + (size_t)b * T_ * T_ + (size_t)(br * 256) * T_;
    const ushort* Bm = Vt + (size_t)b * E_ * T_ + (size_t)(bc * 128) * T_;
    const int ksteps = (br + 1) * 4;   // causal K-limit, BK=64

    f32x4 acc[8][4];
#pragma unroll
    for (int i = 0; i < 8; ++i)
#pragma unroll
        for (int j = 0; j < 4; ++j) acc[i][j] = (f32x4){0.f, 0.f, 0.f, 0.f};

    gemm_tile256x128(A, T_, Bm, T_, ksteps, acc, As, Bs);

    const int lane = threadIdx.x & 63, wave = threadIdx.x >> 6;
    const int wr = (wave >> 1) * 128, wc = (wave & 1) * 64;
    const int frow = lane & 15, q4 = lane >> 4;
    float* Ob = O + (size_t)b * T_ * E_;
#pragma unroll
    for (int mi = 0; mi < 8; ++mi)
#pragma unroll
        for (int r = 0; r < 4; ++r) {
            const int row = br * 256 + wr + mi * 16 + q4 * 4 + r;
#pragma unroll
            for (int ni = 0; ni < 4; ++ni) {
                const int col = bc * 128 + wc + ni * 16 + frow;
                Ob[(size_t)row * E_ + col] = acc[mi][ni][r];
            }
        }
}

// ---------------------------------------------------------------------------
extern "C" void kernel_launch(void* const* d_in, const int* in_sizes, int n_in,
                              void* d_out, int out_size, void* d_ws, size_t ws_size,
                              hipStream_t stream)
{
    const float* q  = (const float*)d_in[0];
    const float* k  = (const float*)d_in[1];
    const float* v  = (const float*)d_in[2];
    const float* Wq = (const float*)d_in[3];
    const float* Wk = (const float*)d_in[4];
    const float* Wv = (const float*)d_in[5];
    float* out = (float*)d_out;

    const size_t nQKV = (size_t)B_ * T_ * E_;      // 16,777,216 elems
    const size_t nW   = (size_t)E_ * E_;
    ushort* Q  = (ushort*)d_ws;
    ushort* K  = Q + nQKV;
    ushort* Vt = K + nQKV;
    ushort* S  = Vt + nQKV;                        // 67 MB
    ushort* Wb = S;                                // weights alias dead S region

    cvtW_kernel<<<dim3(nW / 2048, 3), 256, 0, stream>>>(Wq, Wk, Wv, Wb);
    proj_kernel<<<dim3(128, 8, 3), 256, 0, stream>>>(q, k, v, Wb, Q, K, Vt);
    score_kernel<<<dim3(72, B_), 256, 0, stream>>>(Q, K, S);
    softmax_kernel<<<dim3(B_ * T_), 256, 0, stream>>>(S);
    out_kernel<<<dim3(8, 8, B_), 256, 0, stream>>>(S, Vt, out);
}